// Round 1
// baseline (1546.477 us; speedup 1.0000x reference)
//
#include <hip/hip_runtime.h>
#include <stdint.h>
#include <stddef.h>

// ---------------------------------------------------------------------------
// MMRecBlock on MI355X. Harness buffers are fp32 (reference dtype). We convert
// weights/activations to bf16 in workspace for MFMA GEMMs, accumulate fp32,
// keep gamma / x_residual / outputs fp32. Workspace: ~296 MB.
//
// R1: big GEMMs moved to gemm8_k — BM=128 x BN=256, BK=32, 512 thr (8 waves
// 2x4), 3-deep LDS pipeline with counted s_waitcnt vmcnt(3) (T3+T4), LDS
// granule XOR-swizzle via pre-swizzled global source (T2, rule #21),
// s_setprio around MFMA cluster (T5), bijective XCD block swizzle (T1).
// ---------------------------------------------------------------------------

#define DEV __device__ __forceinline__

typedef __attribute__((ext_vector_type(8))) short bh8;     // 8 x bf16
typedef __attribute__((ext_vector_type(4))) float f32x4;   // MFMA acc

typedef __attribute__((address_space(1))) uint32_t gu32;
typedef __attribute__((address_space(3))) uint32_t lu32;

DEV void async16(const void* g, void* l) {
  __builtin_amdgcn_global_load_lds((gu32*)g, (lu32*)l, 16, 0, 0);
}

DEV float b2f(short s) {
  union { float f; uint32_t u; } x;
  x.u = ((uint32_t)(uint16_t)s) << 16;
  return x.f;
}
DEV short f2b(float f) {  // RNE
  uint32_t u = __float_as_uint(f);
  u += 0x7fffu + ((u >> 16) & 1u);
  return (short)(u >> 16);
}
DEV float sigmoid_f(float x) { return 1.f / (1.f + __expf(-x)); }
DEV float gelu_f(float x) {   // tanh approximation (jax.nn.gelu default)
  float y = 0.7978845608028654f * (x + 0.044715f * x * x * x);
  float t = 1.f - 2.f / (__expf(2.f * y) + 1.f);
  return 0.5f * x * (1.f + t);
}

// shared epilogue
// EPI: 0 = bf16(acc+bias)            1 = bf16(gelu(acc+bias))
//      2 = f32(acc+bias)             3 = f32(sigmoid(acc+bias+f32 aux0))
//      4 = f32(acc+bias+f32 aux0+bf16 aux1)    5 = f32(acc+bias+f32 aux0)
template <int EPI>
DEV void epi_store(float v, size_t idx, void* Cv, const void* aux0, const void* aux1) {
  if constexpr (EPI == 0) {
    ((short*)Cv)[idx] = f2b(v);
  } else if constexpr (EPI == 1) {
    ((short*)Cv)[idx] = f2b(gelu_f(v));
  } else if constexpr (EPI == 2) {
    ((float*)Cv)[idx] = v;
  } else if constexpr (EPI == 3) {
    ((float*)Cv)[idx] = sigmoid_f(v + ((const float*)aux0)[idx]);
  } else if constexpr (EPI == 4) {
    ((float*)Cv)[idx] = v + ((const float*)aux0)[idx] + b2f(((const short*)aux1)[idx]);
  } else {
    ((float*)Cv)[idx] = v + ((const float*)aux0)[idx];
  }
}

// ---------------------------------------------------------------------------
// gemm8_k: C[M,N] = A[M,K] @ B[K,N] (+bias, epilogue). A row-major bf16,
// Bt = B^T row-major [N][K] bf16. Requires M%128==0, N%256==0, K%32==0,
// K>=96, and (M/128)*(N/256)%8==0 for the XCD swizzle.
//
// 512 threads = 8 waves (2 M x 4 N), per-wave 64x64 C via 4x4
// mfma_f32_16x16x32_bf16. BK=32. LDS: 3 buffers (A 8KB + B 16KB each) = 72KB.
// Pipeline: stage tile t+2 while computing tile t; ONE raw s_barrier per
// K-step; counted vmcnt(3) at loop head (never 0 until the last tile).
// LDS swizzle: 16B-granule g' = g ^ ((row>>1)&3); applied on the global
// SOURCE address at stage time (dest stays linear for global_load_lds) and
// on the ds_read address (both sides, same involution).
// ---------------------------------------------------------------------------
template <int EPI>
__global__ __launch_bounds__(512) void gemm8_k(
    const short* __restrict__ A, const short* __restrict__ Bt,
    const float* __restrict__ bias, void* Cv,
    const void* aux0, const void* aux1, int M, int N, int K) {
  __shared__ __align__(16) short sA[3 * 128 * 32];
  __shared__ __align__(16) short sB[3 * 256 * 32];
  const int tid  = threadIdx.x;
  const int lane = tid & 63;
  const int wave = tid >> 6;
  const int q = lane >> 4;   // 0..3
  const int r = lane & 15;   // 0..15
  const int wm = wave >> 2;  // 0..1
  const int wn = wave & 3;   // 0..3

  // T1: bijective XCD swizzle (nwg % 8 == 0 for every launch below)
  const int nwg = gridDim.x * gridDim.y;
  int flat = blockIdx.y * gridDim.x + blockIdx.x;
  flat = (flat & 7) * (nwg >> 3) + (flat >> 3);
  const int bx = flat % gridDim.x;
  const int by = flat / gridDim.x;
  const int m0 = by * 128;
  const int n0 = bx * 256;

  // staging sources: thread covers 16B = 8 bf16. Linear LDS dest (row,g) with
  // row = tid>>2, g = tid&3; source granule = g ^ ((row>>1)&3).
  const int arow = tid >> 2;   // 0..127
  const int ag   = tid & 3;
  const int sga  = ag ^ ((arow >> 1) & 3);
  const int brow1 = 128 + arow;
  const int sgb1 = ag ^ ((brow1 >> 1) & 3);
  const short* srcA  = A  + (size_t)(m0 + arow) * K + sga * 8;
  const short* srcB0 = Bt + (size_t)(n0 + arow) * K + sga * 8;
  const short* srcB1 = Bt + (size_t)(n0 + brow1) * K + sgb1 * 8;
  short* dstA  = &sA[tid * 8];           // + buf*4096
  short* dstB0 = &sB[tid * 8];           // + buf*8192
  short* dstB1 = &sB[4096 + tid * 8];    // + buf*8192

#define STAGE8(bufi, t)                                  \
  do {                                                   \
    const int ko_ = (t) * 32;                            \
    async16(srcA + ko_, dstA + (bufi) * 4096);           \
    async16(srcB0 + ko_, dstB0 + (bufi) * 8192);         \
    async16(srcB1 + ko_, dstB1 + (bufi) * 8192);         \
  } while (0)

  // ds_read addressing: frag rows wm*64 + i*16 + r (A) / wn*64 + j*16 + r (B),
  // granule = q ^ ((row>>1)&3) = q ^ ((r>>1)&3) since bases are mult. of 8.
  const int colg8 = (q ^ ((r >> 1) & 3)) * 8;
  const int aoffb = (wm * 64 + r) * 32 + colg8;   // + i*512
  const int boffb = (wn * 64 + r) * 32 + colg8;   // + j*512

  f32x4 acc[4][4] = {};
  const int NT = K >> 5;

  STAGE8(0, 0);
  STAGE8(1, 1);
  int cb = 0;  // buffer holding tile t
  int pb = 2;  // buffer receiving tile t+2

  for (int t = 0; t < NT; ++t) {
    // T4: counted wait — tile t landed iff all but the newest 3 loads retired.
    if (t == NT - 1) asm volatile("s_waitcnt vmcnt(0)" ::: "memory");
    else             asm volatile("s_waitcnt vmcnt(3)" ::: "memory");
    __builtin_amdgcn_s_barrier();   // all waves: tile t ready, tile t-1 reads done
    asm volatile("" ::: "memory");
    if (t + 2 < NT) STAGE8(pb, t + 2);

    const short* bA = &sA[cb * 4096];
    const short* bB = &sB[cb * 8192];
    bh8 af[4], bf[4];
#pragma unroll
    for (int i = 0; i < 4; ++i) af[i] = *(const bh8*)&bA[aoffb + i * 512];
#pragma unroll
    for (int j = 0; j < 4; ++j) bf[j] = *(const bh8*)&bB[boffb + j * 512];

    __builtin_amdgcn_s_setprio(1);  // T5
#pragma unroll
    for (int i = 0; i < 4; ++i)
#pragma unroll
      for (int j = 0; j < 4; ++j)
        acc[i][j] = __builtin_amdgcn_mfma_f32_16x16x32_bf16(af[i], bf[j], acc[i][j], 0, 0, 0);
    __builtin_amdgcn_s_setprio(0);
    asm volatile("" ::: "memory");

    cb = (cb == 2) ? 0 : cb + 1;
    pb = (pb == 2) ? 0 : pb + 1;
  }
#undef STAGE8

#pragma unroll
  for (int j = 0; j < 4; ++j) {
    const int col = n0 + wn * 64 + j * 16 + r;
    const float bv = bias[col];
#pragma unroll
    for (int i = 0; i < 4; ++i) {
#pragma unroll
      for (int rr = 0; rr < 4; ++rr) {
        const int row = m0 + wm * 64 + i * 16 + q * 4 + rr;
        const size_t idx = (size_t)row * N + col;
        epi_store<EPI>(acc[i][j][rr] + bv, idx, Cv, aux0, aux1);
      }
    }
  }
}

// ---------------------------------------------------------------------------
// gemm_k (legacy 128x128): kept for small shapes (md1 N=512, ka/va M=128).
// ---------------------------------------------------------------------------
template <int EPI>
__global__ __launch_bounds__(256) void gemm_k(
    const short* __restrict__ A, const short* __restrict__ Bt,
    const float* __restrict__ bias, void* Cv,
    const void* aux0, const void* aux1, int M, int N, int K) {
  __shared__ __align__(16) short sA[128 * 32];
  __shared__ __align__(16) short sB[128 * 32];
  const int tid  = threadIdx.x;
  const int lane = tid & 63;
  const int wave = tid >> 6;
  const int q = lane >> 4;   // 0..3
  const int r = lane & 15;   // 0..15
  const int m0 = blockIdx.y * 128;
  const int n0 = blockIdx.x * 128;
  const int wm = (wave >> 1) * 64;
  const int wn = (wave & 1) * 64;

  const int L0 = tid, L1 = 256 + tid;
  const short* gA0 = A + (size_t)(m0 + (L0 >> 2)) * K + (L0 & 3) * 8;
  const short* gA1 = A + (size_t)(m0 + (L1 >> 2)) * K + (L1 & 3) * 8;
  const short* gB0 = Bt + (size_t)(n0 + (L0 >> 2)) * K + (L0 & 3) * 8;
  const short* gB1 = Bt + (size_t)(n0 + (L1 >> 2)) * K + (L1 & 3) * 8;
  short* lA0 = &sA[L0 * 8];
  short* lA1 = &sA[L1 * 8];
  short* lB0 = &sB[L0 * 8];
  short* lB1 = &sB[L1 * 8];

  f32x4 acc[4][4] = {};
  const int nk = K >> 5;
  for (int kt = 0; kt < nk; ++kt) {
    __syncthreads();
    const int kb = kt << 5;
    async16(gA0 + kb, lA0);
    async16(gA1 + kb, lA1);
    async16(gB0 + kb, lB0);
    async16(gB1 + kb, lB1);
    asm volatile("s_waitcnt vmcnt(0)" ::: "memory");
    __syncthreads();
    bh8 af[4], bf[4];
#pragma unroll
    for (int i = 0; i < 4; ++i)
      af[i] = *(const bh8*)&sA[(wm + i * 16 + r) * 32 + q * 8];
#pragma unroll
    for (int j = 0; j < 4; ++j)
      bf[j] = *(const bh8*)&sB[(wn + j * 16 + r) * 32 + q * 8];
#pragma unroll
    for (int i = 0; i < 4; ++i)
#pragma unroll
      for (int j = 0; j < 4; ++j)
        acc[i][j] = __builtin_amdgcn_mfma_f32_16x16x32_bf16(af[i], bf[j], acc[i][j], 0, 0, 0);
  }

#pragma unroll
  for (int j = 0; j < 4; ++j) {
    const int col = n0 + wn + j * 16 + r;
    const float bv = bias[col];
#pragma unroll
    for (int i = 0; i < 4; ++i) {
#pragma unroll
      for (int rr = 0; rr < 4; ++rr) {
        const int row = m0 + wm + i * 16 + q * 4 + rr;
        const size_t idx = (size_t)row * N + col;
        epi_store<EPI>(acc[i][j][rr] + bv, idx, Cv, aux0, aux1);
      }
    }
  }
}

// ---------------------------------------------------------------------------
// fp32 -> bf16 transpose: out[C][R] = bf16(in[R][C]).  64x64 tiles, (16,16).
// ---------------------------------------------------------------------------
__global__ __launch_bounds__(256) void transpose_k(const float* __restrict__ in,
                                                   short* __restrict__ out,
                                                   int R, int C) {
  __shared__ float t[64][68];
  const int tx = threadIdx.x, ty = threadIdx.y;
  const int c0 = blockIdx.x * 64, r0 = blockIdx.y * 64;
#pragma unroll
  for (int yy = 0; yy < 64; yy += 16) {
    const float4 v = *(const float4*)&in[(size_t)(r0 + ty + yy) * C + c0 + tx * 4];
    t[ty + yy][tx * 4 + 0] = v.x;
    t[ty + yy][tx * 4 + 1] = v.y;
    t[ty + yy][tx * 4 + 2] = v.z;
    t[ty + yy][tx * 4 + 3] = v.w;
  }
  __syncthreads();
#pragma unroll
  for (int yy = 0; yy < 64; yy += 16) {
    short4 v;
    v.x = f2b(t[tx * 4 + 0][ty + yy]);
    v.y = f2b(t[tx * 4 + 1][ty + yy]);
    v.z = f2b(t[tx * 4 + 2][ty + yy]);
    v.w = f2b(t[tx * 4 + 3][ty + yy]);
    *(short4*)&out[(size_t)(c0 + ty + yy) * R + r0 + tx * 4] = v;
  }
}

// ---------------------------------------------------------------------------
// fp32 -> bf16 convert (4 elems/thread)
// ---------------------------------------------------------------------------
__global__ __launch_bounds__(256) void cvt_k(const float* __restrict__ in,
                                             short* __restrict__ out) {
  const size_t i = ((size_t)blockIdx.x * 256 + threadIdx.x) * 4;
  const float4 v = *(const float4*)(in + i);
  short4 o;
  o.x = f2b(v.x); o.y = f2b(v.y); o.z = f2b(v.z); o.w = f2b(v.w);
  *(short4*)(out + i) = o;
}

// ---------------------------------------------------------------------------
// RMSNorm row kernel (D=2048), fp32 in, fp32 weight, bf16 out.
// ---------------------------------------------------------------------------
__global__ __launch_bounds__(256) void rmsnorm_k(const float* __restrict__ in,
                                                 const float* __restrict__ w,
                                                 short* __restrict__ out) {
  const int row = blockIdx.x;
  const int tid = threadIdx.x;
  const size_t base = (size_t)row * 2048;
  float v[8];
  const float* p = in + base + tid * 8;
#pragma unroll
  for (int i = 0; i < 8; ++i) v[i] = p[i];
  float ss = 0.f;
#pragma unroll
  for (int i = 0; i < 8; ++i) ss += v[i] * v[i];
  for (int off = 32; off; off >>= 1) ss += __shfl_down(ss, off);
  __shared__ float red[4];
  __shared__ float sscale;
  if ((tid & 63) == 0) red[tid >> 6] = ss;
  __syncthreads();
  if (tid == 0) {
    float tot = red[0] + red[1] + red[2] + red[3];
    sscale = 1.f / (sqrtf(tot * (1.f / 2048.f)) + 1e-6f);
  }
  __syncthreads();
  const float scale = sscale;
  short* o = out + base + tid * 8;
#pragma unroll
  for (int i = 0; i < 8; ++i) o[i] = f2b(w[tid * 8 + i] * v[i] * scale);
}

// ---------------------------------------------------------------------------
// h_t = z * sigmoid(gpre) + gamma * x   (z,gpre bf16; gamma,x fp32; ht bf16)
// ---------------------------------------------------------------------------
__global__ __launch_bounds__(256) void ht_k(const short* __restrict__ z,
                                            const short* __restrict__ gp,
                                            const float* __restrict__ gamma,
                                            const float* __restrict__ x,
                                            short* __restrict__ ht) {
  const size_t i = ((size_t)blockIdx.x * 256 + threadIdx.x) * 4;
  const short4 z4 = *(const short4*)(z + i);
  const short4 g4 = *(const short4*)(gp + i);
  const float4 x4 = *(const float4*)(x + i);
  const float4 gm = *(const float4*)(gamma + i);
  short4 o;
  o.x = f2b(b2f(z4.x) * sigmoid_f(b2f(g4.x)) + gm.x * x4.x);
  o.y = f2b(b2f(z4.y) * sigmoid_f(b2f(g4.y)) + gm.y * x4.y);
  o.z = f2b(b2f(z4.z) * sigmoid_f(b2f(g4.z)) + gm.z * x4.z);
  o.w = f2b(b2f(z4.w) * sigmoid_f(b2f(g4.w)) + gm.w * x4.w);
  *(short4*)(ht + i) = o;
}

// ---------------------------------------------------------------------------
// cumprod over the reshaped (B,H,S,dh) view, axis=2.
// ---------------------------------------------------------------------------
__global__ __launch_bounds__(128) void cumprod1_k(float* __restrict__ gamma,
                                                  float* __restrict__ segprod) {
  const int bx = blockIdx.x;           // b*128 + h*8 + seg
  const int b = bx >> 7, h = (bx >> 3) & 15, seg = bx & 7;
  size_t base = (size_t)b * 4194304 + (size_t)h * 262144 + (size_t)seg * 256 * 128 + threadIdx.x;
  float acc = 1.f;
  for (int s = 0; s < 256; ++s) {
    acc *= gamma[base + (size_t)s * 128];
    gamma[base + (size_t)s * 128] = acc;
  }
  segprod[(size_t)bx * 128 + threadIdx.x] = acc;
}

__global__ __launch_bounds__(128) void cumprod2_k(const float* __restrict__ gamma,
                                                  const float* __restrict__ segprod,
                                                  float* __restrict__ out) {
  const int bx = blockIdx.x;
  const int b = bx >> 7, h = (bx >> 3) & 15, seg = bx & 7;
  size_t base = (size_t)b * 4194304 + (size_t)h * 262144 + (size_t)seg * 256 * 128 + threadIdx.x;
  float pre = 1.f;
  const size_t sp0 = (size_t)(bx & ~7) * 128 + threadIdx.x;
  for (int t = 0; t < seg; ++t) pre *= segprod[sp0 + (size_t)t * 128];
  for (int s = 0; s < 256; ++s)
    out[base + (size_t)s * 128] = gamma[base + (size_t)s * 128] * pre;
}

// ---------------------------------------------------------------------------
// Memory attention: per (b,h), 32 query rows/block, M=64 mem tokens, dh=128.
// ---------------------------------------------------------------------------
__global__ __launch_bounds__(512) void attn_k(const short* __restrict__ qa,
                                              const short* __restrict__ ka,
                                              const short* __restrict__ va,
                                              short* __restrict__ ctx) {
  __shared__ short sk[64][136];
  __shared__ short sv[64][136];
  __shared__ float sq[32][128];
  __shared__ float ss[32][64];
  const int tid = threadIdx.x;
  const int b = blockIdx.z, h = blockIdx.y;
  const int s0 = blockIdx.x * 32;
  const size_t hoff = (size_t)h * 128;
  for (int i = tid; i < 64 * 128; i += 512) {
    int m = i >> 7, d = i & 127;
    sk[m][d] = ka[((size_t)b * 64 + m) * 2048 + hoff + d];
    sv[m][d] = va[((size_t)b * 64 + m) * 2048 + hoff + d];
  }
  for (int i = tid; i < 32 * 128; i += 512) {
    int s = i >> 7, d = i & 127;
    sq[s][d] = b2f(qa[((size_t)b * 2048 + s0 + s) * 2048 + hoff + d]);
  }
  __syncthreads();
  const int g = tid >> 4;  // query row within block
  const int t = tid & 15;
  float sc[4];
#pragma unroll
  for (int mi = 0; mi < 4; ++mi) {
    const int m = mi * 16 + t;
    float a = 0.f;
    for (int d = 0; d < 128; ++d) a += sq[g][d] * b2f(sk[m][d]);
    sc[mi] = a * 0.08838834764831843f;  // 1/sqrt(128)
  }
  float mx = fmaxf(fmaxf(sc[0], sc[1]), fmaxf(sc[2], sc[3]));
#pragma unroll
  for (int off = 8; off; off >>= 1) mx = fmaxf(mx, __shfl_xor(mx, off, 16));
  float sum = 0.f;
#pragma unroll
  for (int mi = 0; mi < 4; ++mi) { sc[mi] = __expf(sc[mi] - mx); sum += sc[mi]; }
#pragma unroll
  for (int off = 8; off; off >>= 1) sum += __shfl_xor(sum, off, 16);
  const float inv = 1.f / sum;
#pragma unroll
  for (int mi = 0; mi < 4; ++mi) ss[g][mi * 16 + t] = sc[mi] * inv;
  __syncthreads();
  const int d0 = t * 8;
  float o[8] = {};
  for (int m = 0; m < 64; ++m) {
    const float wgt = ss[g][m];
#pragma unroll
    for (int i = 0; i < 8; ++i) o[i] += wgt * b2f(sv[m][d0 + i]);
  }
  short* op = ctx + ((size_t)b * 2048 + s0 + g) * 2048 + hoff + d0;
#pragma unroll
  for (int i = 0; i < 8; ++i) op[i] = f2b(o[i]);
}

// ---------------------------------------------------------------------------
extern "C" void kernel_launch(void* const* d_in, const int* in_sizes, int n_in,
                              void* d_out, int out_size, void* d_ws, size_t ws_size,
                              hipStream_t stream) {
  (void)in_sizes; (void)n_in; (void)out_size; (void)ws_size;
  // inputs (setup_inputs dict order, all fp32); wq/bq and wv/bv are dead
  const float* x   = (const float*)d_in[0];
  const float* mem = (const float*)d_in[1];
  const float* wk  = (const float*)d_in[3];
  const float* wz  = (const float*)d_in[5];
  const float* wg  = (const float*)d_in[6];
  const float* md1 = (const float*)d_in[7];
  const float* md2 = (const float*)d_in[8];
  const float* mcw = (const float*)d_in[9];
  const float* awq = (const float*)d_in[10];
  const float* awk = (const float*)d_in[11];
  const float* awv = (const float*)d_in[12];
  const float* awo = (const float*)d_in[13];
  const float* f1  = (const float*)d_in[14];
  const float* f2  = (const float*)d_in[15];
  const float* bk  = (const float*)d_in[17];
  const float* bz  = (const float*)d_in[19];
  const float* bg  = (const float*)d_in[20];
  const float* mb1 = (const float*)d_in[21];
  const float* mb2 = (const float*)d_in[22];
  const float* mcb = (const float*)d_in[23];
  const float* abq = (const float*)d_in[24];
  const float* abk = (const float*)d_in[25];
  const float* abv = (const float*)d_in[26];
  const float* abo = (const float*)d_in[27];
  const float* fb1 = (const float*)d_in[28];
  const float* fb2 = (const float*)d_in[29];
  const float* n1w = (const float*)d_in[30];
  const float* n2w = (const float*)d_in[31];

  // workspace layout (bytes); total ~296 MB
  char* W = (char*)d_ws;
  short* wkT  = (short*)(W + 0);
  short* wzT  = (short*)(W + 8388608);
  short* wgT  = (short*)(W + 16777216);
  short* mcwT = (short*)(W + 25165824);
  short* md1T = (short*)(W + 33554432);
  short* md2T = (short*)(W + 35651584);
  short* awqT = (short*)(W + 37748736);
  short* awkT = (short*)(W + 46137344);
  short* awvT = (short*)(W + 54525952);
  short* awoT = (short*)(W + 62914560);
  short* f1T  = (short*)(W + 71303168);
  short* f2T  = (short*)(W + 104857600);
  char*  big  = W + 138412032;               // 64 MB region, reused as t2
  short* xn   = (short*)(big + 0);
  short* kk   = (short*)(big + 16777216);    // later: ctx
  short* z    = (short*)(big + 33554432);
  short* gpre = (short*)(big + 50331648);
  short* ctx  = kk;
  short* t2   = (short*)big;
  short* t1   = (short*)(W + 205520896);
  float* gamma = (float*)(W + 209715200);    // later: xres (fp32)
  float* xres  = gamma;
  short* ht   = (short*)(W + 243269632);
  short* qa   = (short*)(W + 260046848);
  short* xn2  = qa;
  short* xb   = (short*)(W + 276824064);
  short* memb = (short*)(W + 293601280);
  short* ka   = (short*)(W + 294125568);
  short* va   = (short*)(W + 294649856);
  float* segprod = (float*)(W + 295174144);

  float* out0 = (float*)d_out;               // output  (B,S,D) fp32
  float* out1 = out0 + 8388608;              // cumprod (B,S,D) fp32

  const dim3 tb16(16, 16);
  // 1) weight transposes (fp32 -> bf16, Bt layout [N][K])
  transpose_k<<<dim3(32, 32), tb16, 0, stream>>>(wk, wkT, 2048, 2048);
  transpose_k<<<dim3(32, 32), tb16, 0, stream>>>(wz, wzT, 2048, 2048);
  transpose_k<<<dim3(32, 32), tb16, 0, stream>>>(wg, wgT, 2048, 2048);
  transpose_k<<<dim3(32, 32), tb16, 0, stream>>>(mcw, mcwT, 2048, 2048);
  transpose_k<<<dim3(8, 32), tb16, 0, stream>>>(md1, md1T, 2048, 512);
  transpose_k<<<dim3(32, 8), tb16, 0, stream>>>(md2, md2T, 512, 2048);
  transpose_k<<<dim3(32, 32), tb16, 0, stream>>>(awq, awqT, 2048, 2048);
  transpose_k<<<dim3(32, 32), tb16, 0, stream>>>(awk, awkT, 2048, 2048);
  transpose_k<<<dim3(32, 32), tb16, 0, stream>>>(awv, awvT, 2048, 2048);
  transpose_k<<<dim3(32, 32), tb16, 0, stream>>>(awo, awoT, 2048, 2048);
  transpose_k<<<dim3(128, 32), tb16, 0, stream>>>(f1, f1T, 2048, 8192);
  transpose_k<<<dim3(32, 128), tb16, 0, stream>>>(f2, f2T, 8192, 2048);

  // 2) converts + first norm
  cvt_k<<<8192, 256, 0, stream>>>(x, xb);
  cvt_k<<<256, 256, 0, stream>>>(mem, memb);
  rmsnorm_k<<<4096, 256, 0, stream>>>(x, n1w, xn);

  // 3-5) projections (gemm8: grid (N/256, M/128))
  gemm8_k<0><<<dim3(8, 32), 512, 0, stream>>>(xn, wkT, bk, kk, nullptr, nullptr, 4096, 2048, 2048);
  gemm8_k<0><<<dim3(8, 32), 512, 0, stream>>>(xn, wzT, bz, z, nullptr, nullptr, 4096, 2048, 2048);
  gemm8_k<0><<<dim3(8, 32), 512, 0, stream>>>(xb, wgT, bg, gpre, nullptr, nullptr, 4096, 2048, 2048);

  // 6-8) gamma = sigmoid(gelu(z@md1+mb1)@md2 + mb2 + k_@mcw + mcb)
  gemm_k<1><<<dim3(4, 32), 256, 0, stream>>>(z, md1T, mb1, t1, nullptr, nullptr, 4096, 512, 2048);
  gemm8_k<2><<<dim3(8, 32), 512, 0, stream>>>(t1, md2T, mb2, gamma, nullptr, nullptr, 4096, 2048, 512);
  gemm8_k<3><<<dim3(8, 32), 512, 0, stream>>>(kk, mcwT, mcb, gamma, gamma, nullptr, 4096, 2048, 2048);

  // 9) h_t = z*sigmoid(gpre) + gamma*x   (before cumprod destroys gamma)
  ht_k<<<8192, 256, 0, stream>>>(z, gpre, gamma, x, ht);

  // 10-11) cumprod -> out1 (fp32)
  cumprod1_k<<<256, 128, 0, stream>>>(gamma, segprod);
  cumprod2_k<<<256, 128, 0, stream>>>(gamma, segprod, out1);

  // 12-14) attention projections
  gemm8_k<0><<<dim3(8, 32), 512, 0, stream>>>(ht, awqT, abq, qa, nullptr, nullptr, 4096, 2048, 2048);
  gemm_k<0><<<dim3(16, 1), 256, 0, stream>>>(memb, awkT, abk, ka, nullptr, nullptr, 128, 2048, 2048);
  gemm_k<0><<<dim3(16, 1), 256, 0, stream>>>(memb, awvT, abv, va, nullptr, nullptr, 128, 2048, 2048);

  // 15) attention -> ctx
  attn_k<<<dim3(64, 16, 2), 512, 0, stream>>>(qa, ka, va, ctx);

  // 16) xres = ctx@awo + abo + x + ht   (fp32)
  gemm8_k<4><<<dim3(8, 32), 512, 0, stream>>>(ctx, awoT, abo, xres, x, ht, 4096, 2048, 2048);

  // 17) xn2 = rmsnorm(xres, n2w)
  rmsnorm_k<<<4096, 256, 0, stream>>>(xres, n2w, xn2);

  // 18-19) FFN: out0 = xres + gelu(xn2@f1+fb1)@f2 + fb2
  gemm8_k<1><<<dim3(32, 32), 512, 0, stream>>>(xn2, f1T, fb1, t2, nullptr, nullptr, 4096, 8192, 2048);
  gemm8_k<5><<<dim3(8, 32), 512, 0, stream>>>(t2, f2T, fb2, out0, xres, nullptr, 4096, 2048, 8192);
}

// Round 2
// 1207.171 us; speedup vs baseline: 1.2811x; 1.2811x over previous
//
#include <hip/hip_runtime.h>
#include <stdint.h>
#include <stddef.h>

// ---------------------------------------------------------------------------
// MMRecBlock on MI355X. Harness buffers are fp32 (reference dtype). We convert
// weights/activations to bf16 in workspace for MFMA GEMMs, accumulate fp32,
// keep gamma / x_residual / outputs fp32. Workspace: ~296 MB.
//
// R2: gemm8_k rebuilt as a 3-buffer free-running pipeline. BM=128 x BN=256,
// BK=64, 512 thr (8 waves 2Mx4N, 64x64 C each). Stage tile t+2 into LDS buf
// (t+2)%3 while computing tile t from buf t%3 -> staged buffer is untouched
// for 2 full tiles => NO intra-tile write/read hazard, no drain. One counted
// s_waitcnt vmcnt(6) + one raw s_barrier per K-tile (T4); waves free-run
// within a tile so ds_read and MFMA overlap across waves. Granule XOR swizzle
// kept on both sides (T2); bijective XCD swizzle kept (T1). LDS = 3x48KB.
// ---------------------------------------------------------------------------

#define DEV __device__ __forceinline__

typedef __attribute__((ext_vector_type(8))) short bh8;     // 8 x bf16
typedef __attribute__((ext_vector_type(4))) float f32x4;   // MFMA acc

typedef __attribute__((address_space(1))) uint32_t gu32;
typedef __attribute__((address_space(3))) uint32_t lu32;

DEV void async16(const void* g, void* l) {
  __builtin_amdgcn_global_load_lds((gu32*)g, (lu32*)l, 16, 0, 0);
}

DEV float b2f(short s) {
  union { float f; uint32_t u; } x;
  x.u = ((uint32_t)(uint16_t)s) << 16;
  return x.f;
}
DEV short f2b(float f) {  // RNE
  uint32_t u = __float_as_uint(f);
  u += 0x7fffu + ((u >> 16) & 1u);
  return (short)(u >> 16);
}
DEV float sigmoid_f(float x) { return 1.f / (1.f + __expf(-x)); }
DEV float gelu_f(float x) {   // tanh approximation (jax.nn.gelu default)
  float y = 0.7978845608028654f * (x + 0.044715f * x * x * x);
  float t = 1.f - 2.f / (__expf(2.f * y) + 1.f);
  return 0.5f * x * (1.f + t);
}

// shared epilogue
// EPI: 0 = bf16(acc+bias)            1 = bf16(gelu(acc+bias))
//      2 = f32(acc+bias)             3 = f32(sigmoid(acc+bias+f32 aux0))
//      4 = f32(acc+bias+f32 aux0+bf16 aux1)    5 = f32(acc+bias+f32 aux0)
template <int EPI>
DEV void epi_store(float v, size_t idx, void* Cv, const void* aux0, const void* aux1) {
  if constexpr (EPI == 0) {
    ((short*)Cv)[idx] = f2b(v);
  } else if constexpr (EPI == 1) {
    ((short*)Cv)[idx] = f2b(gelu_f(v));
  } else if constexpr (EPI == 2) {
    ((float*)Cv)[idx] = v;
  } else if constexpr (EPI == 3) {
    ((float*)Cv)[idx] = sigmoid_f(v + ((const float*)aux0)[idx]);
  } else if constexpr (EPI == 4) {
    ((float*)Cv)[idx] = v + ((const float*)aux0)[idx] + b2f(((const short*)aux1)[idx]);
  } else {
    ((float*)Cv)[idx] = v + ((const float*)aux0)[idx];
  }
}

// ---------------------------------------------------------------------------
// gemm8_k: C[M,N] = A[M,K] @ B[K,N] (+bias, epilogue). A row-major bf16,
// Bt = B^T row-major [N][K] bf16. Requires M%128==0, N%256==0, K%64==0.
//
// Geometry: BM=128, BN=256, BK=64. 512 threads = 8 waves (2M x 4N), per-wave
// 64x64 C via 4x4 frags of mfma_f32_16x16x32_bf16, 2 K-substeps per tile.
// LDS per buffer: A[128][64] (16KB) + B[256][64] (32KB) = 48KB; 3 buffers.
// Per K-tile per thread: 16 ds_read_b128 + 6 global_load_lds (4 B + 2 A).
//
// Pipeline invariant: buffer (t+2)%3 is written while buffers t%3 (reading)
// and (t+1)%3 (landed/landing) are in use. s_waitcnt vmcnt(6) at tile end
// leaves exactly tile-(t+2)'s 6 loads in flight => tile t+1 fully landed
// before the barrier that releases its readers. Tail: vmcnt(0) when t+2>=NT.
//
// LDS swizzle: 16B granule gL at row holds logical k-granule gL^(row&7);
// applied by pre-swizzling the GLOBAL source (linear LDS dest, rule #21) and
// XOR-ing the ds_read address with the same involution.
// ---------------------------------------------------------------------------
template <int EPI>
__global__ __launch_bounds__(512) void gemm8_k(
    const short* __restrict__ A, const short* __restrict__ Bt,
    const float* __restrict__ bias, void* Cv,
    const void* aux0, const void* aux1, int M, int N, int K) {
  __shared__ __align__(16) short sL[3 * 24576];   // 144 KB
  const int tid  = threadIdx.x;
  const int lane = tid & 63;
  const int wave = tid >> 6;
  const int q = lane >> 4;   // 0..3
  const int r = lane & 15;   // 0..15
  const int wm = wave >> 2;  // 0..1
  const int wn = wave & 3;   // 0..3

  // T1: bijective XCD swizzle (every launch below has nwg % 8 == 0)
  const int nwg = gridDim.x * gridDim.y;
  int flat = blockIdx.y * gridDim.x + blockIdx.x;
  flat = (flat & 7) * (nwg >> 3) + (flat >> 3);
  const int bx = flat % gridDim.x;
  const int by = flat / gridDim.x;
  const int m0 = by * 128;
  const int n0 = bx * 256;

  // staging: thread covers 16B granules; LDS position p -> row=p>>3, gL=p&7,
  // global k-granule = gL ^ (row&7). Thread's extra positions step rows by 64
  // (row&7 invariant -> same XOR).
  const int srow = tid >> 3;                       // 0..63
  const int sk8  = (tid & 7) ^ (srow & 7);
  const short* pA = A  + (size_t)(m0 + srow) * K + sk8 * 8;
  const short* pB = Bt + (size_t)(n0 + srow) * K + sk8 * 8;
  const size_t K64 = (size_t)64 * K;
  short* dA = &sL[tid * 8];            // A region @ 0,    + buf*24576
  short* dB = &sL[8192 + tid * 8];     // B region @ 16KB, + buf*24576

#define STAGE_B(bi, t) do {                        \
    const short* s_ = pB + (size_t)(t) * 64;       \
    short* d_ = dB + (bi) * 24576;                 \
    async16(s_,           d_);                     \
    async16(s_ + K64,     d_ + 4096);              \
    async16(s_ + 2 * K64, d_ + 8192);              \
    async16(s_ + 3 * K64, d_ + 12288);             \
  } while (0)
#define STAGE_A(bi, t) do {                        \
    const short* s_ = pA + (size_t)(t) * 64;       \
    short* d_ = dA + (bi) * 24576;                 \
    async16(s_,       d_);                         \
    async16(s_ + K64, d_ + 4096);                  \
  } while (0)

  // ds_read offsets (in shorts). Row stride = 64 shorts (128B).
  // Frag (i|j, kk): row = w*64 + f*16 + r, granule = (kk*4+q) ^ (r&7).
  const int swz0 = (q ^ (r & 7)) * 8;
  const int swz1 = ((4 + q) ^ (r & 7)) * 8;
  const int aRow = (wm * 64 + r) * 64;
  const int bRow = 8192 + (wn * 64 + r) * 64;

  f32x4 acc[4][4] = {};
  const int NT = K >> 6;

  // prologue: tiles 0 and 1
  STAGE_B(0, 0); STAGE_A(0, 0);
  if (NT > 1) {
    STAGE_B(1, 1); STAGE_A(1, 1);
    asm volatile("s_waitcnt vmcnt(6)" ::: "memory");   // tile0 landed
  } else {
    asm volatile("s_waitcnt vmcnt(0)" ::: "memory");
  }
  __builtin_amdgcn_s_barrier();

  int cb = 0;  // buffer holding tile t
  for (int t = 0; t < NT; ++t) {
    const short* buf = &sL[cb * 24576];
    bh8 af[4][2], bf[4][2];
#pragma unroll
    for (int i = 0; i < 4; ++i) {
      af[i][0] = *(const bh8*)&buf[aRow + i * 1024 + swz0];
      af[i][1] = *(const bh8*)&buf[aRow + i * 1024 + swz1];
    }
#pragma unroll
    for (int j = 0; j < 4; ++j) {
      bf[j][0] = *(const bh8*)&buf[bRow + j * 1024 + swz0];
      bf[j][1] = *(const bh8*)&buf[bRow + j * 1024 + swz1];
    }
    // prefetch tile t+2 into buffer (t+2)%3 — untouched until tile t+2.
    if (t + 2 < NT) {
      const int pb = (cb == 0) ? 2 : cb - 1;
      STAGE_B(pb, t + 2);
      STAGE_A(pb, t + 2);
    }
#pragma unroll
    for (int kk = 0; kk < 2; ++kk)
#pragma unroll
      for (int i = 0; i < 4; ++i)
#pragma unroll
        for (int j = 0; j < 4; ++j)
          acc[i][j] = __builtin_amdgcn_mfma_f32_16x16x32_bf16(
              af[i][kk], bf[j][kk], acc[i][j], 0, 0, 0);
    // T4: counted wait. All loads except tile-(t+2)'s 6 must have retired
    // => tile t+1 fully landed. Tail: drain.
    if (t + 2 < NT) asm volatile("s_waitcnt vmcnt(6)" ::: "memory");
    else            asm volatile("s_waitcnt vmcnt(0)" ::: "memory");
    __builtin_amdgcn_s_barrier();
    cb = (cb == 2) ? 0 : cb + 1;
  }
#undef STAGE_A
#undef STAGE_B

#pragma unroll
  for (int j = 0; j < 4; ++j) {
    const int col = n0 + wn * 64 + j * 16 + r;
    const float bv = bias[col];
#pragma unroll
    for (int i = 0; i < 4; ++i) {
#pragma unroll
      for (int rr = 0; rr < 4; ++rr) {
        const int row = m0 + wm * 64 + i * 16 + q * 4 + rr;
        const size_t idx = (size_t)row * N + col;
        epi_store<EPI>(acc[i][j][rr] + bv, idx, Cv, aux0, aux1);
      }
    }
  }
}

// ---------------------------------------------------------------------------
// fp32 -> bf16 transpose: out[C][R] = bf16(in[R][C]).  64x64 tiles, (16,16).
// ---------------------------------------------------------------------------
__global__ __launch_bounds__(256) void transpose_k(const float* __restrict__ in,
                                                   short* __restrict__ out,
                                                   int R, int C) {
  __shared__ float t[64][68];
  const int tx = threadIdx.x, ty = threadIdx.y;
  const int c0 = blockIdx.x * 64, r0 = blockIdx.y * 64;
#pragma unroll
  for (int yy = 0; yy < 64; yy += 16) {
    const float4 v = *(const float4*)&in[(size_t)(r0 + ty + yy) * C + c0 + tx * 4];
    t[ty + yy][tx * 4 + 0] = v.x;
    t[ty + yy][tx * 4 + 1] = v.y;
    t[ty + yy][tx * 4 + 2] = v.z;
    t[ty + yy][tx * 4 + 3] = v.w;
  }
  __syncthreads();
#pragma unroll
  for (int yy = 0; yy < 64; yy += 16) {
    short4 v;
    v.x = f2b(t[tx * 4 + 0][ty + yy]);
    v.y = f2b(t[tx * 4 + 1][ty + yy]);
    v.z = f2b(t[tx * 4 + 2][ty + yy]);
    v.w = f2b(t[tx * 4 + 3][ty + yy]);
    *(short4*)&out[(size_t)(c0 + ty + yy) * R + r0 + tx * 4] = v;
  }
}

// ---------------------------------------------------------------------------
// fp32 -> bf16 convert (4 elems/thread)
// ---------------------------------------------------------------------------
__global__ __launch_bounds__(256) void cvt_k(const float* __restrict__ in,
                                             short* __restrict__ out) {
  const size_t i = ((size_t)blockIdx.x * 256 + threadIdx.x) * 4;
  const float4 v = *(const float4*)(in + i);
  short4 o;
  o.x = f2b(v.x); o.y = f2b(v.y); o.z = f2b(v.z); o.w = f2b(v.w);
  *(short4*)(out + i) = o;
}

// ---------------------------------------------------------------------------
// RMSNorm row kernel (D=2048), fp32 in, fp32 weight, bf16 out.
// ---------------------------------------------------------------------------
__global__ __launch_bounds__(256) void rmsnorm_k(const float* __restrict__ in,
                                                 const float* __restrict__ w,
                                                 short* __restrict__ out) {
  const int row = blockIdx.x;
  const int tid = threadIdx.x;
  const size_t base = (size_t)row * 2048;
  float v[8];
  const float* p = in + base + tid * 8;
#pragma unroll
  for (int i = 0; i < 8; ++i) v[i] = p[i];
  float ss = 0.f;
#pragma unroll
  for (int i = 0; i < 8; ++i) ss += v[i] * v[i];
  for (int off = 32; off; off >>= 1) ss += __shfl_down(ss, off);
  __shared__ float red[4];
  __shared__ float sscale;
  if ((tid & 63) == 0) red[tid >> 6] = ss;
  __syncthreads();
  if (tid == 0) {
    float tot = red[0] + red[1] + red[2] + red[3];
    sscale = 1.f / (sqrtf(tot * (1.f / 2048.f)) + 1e-6f);
  }
  __syncthreads();
  const float scale = sscale;
  short* o = out + base + tid * 8;
#pragma unroll
  for (int i = 0; i < 8; ++i) o[i] = f2b(w[tid * 8 + i] * v[i] * scale);
}

// ---------------------------------------------------------------------------
// h_t = z * sigmoid(gpre) + gamma * x   (z,gpre bf16; gamma,x fp32; ht bf16)
// ---------------------------------------------------------------------------
__global__ __launch_bounds__(256) void ht_k(const short* __restrict__ z,
                                            const short* __restrict__ gp,
                                            const float* __restrict__ gamma,
                                            const float* __restrict__ x,
                                            short* __restrict__ ht) {
  const size_t i = ((size_t)blockIdx.x * 256 + threadIdx.x) * 4;
  const short4 z4 = *(const short4*)(z + i);
  const short4 g4 = *(const short4*)(gp + i);
  const float4 x4 = *(const float4*)(x + i);
  const float4 gm = *(const float4*)(gamma + i);
  short4 o;
  o.x = f2b(b2f(z4.x) * sigmoid_f(b2f(g4.x)) + gm.x * x4.x);
  o.y = f2b(b2f(z4.y) * sigmoid_f(b2f(g4.y)) + gm.y * x4.y);
  o.z = f2b(b2f(z4.z) * sigmoid_f(b2f(g4.z)) + gm.z * x4.z);
  o.w = f2b(b2f(z4.w) * sigmoid_f(b2f(g4.w)) + gm.w * x4.w);
  *(short4*)(ht + i) = o;
}

// ---------------------------------------------------------------------------
// cumprod over the reshaped (B,H,S,dh) view, axis=2.
// ---------------------------------------------------------------------------
__global__ __launch_bounds__(128) void cumprod1_k(float* __restrict__ gamma,
                                                  float* __restrict__ segprod) {
  const int bx = blockIdx.x;           // b*128 + h*8 + seg
  const int b = bx >> 7, h = (bx >> 3) & 15, seg = bx & 7;
  size_t base = (size_t)b * 4194304 + (size_t)h * 262144 + (size_t)seg * 256 * 128 + threadIdx.x;
  float acc = 1.f;
  for (int s = 0; s < 256; ++s) {
    acc *= gamma[base + (size_t)s * 128];
    gamma[base + (size_t)s * 128] = acc;
  }
  segprod[(size_t)bx * 128 + threadIdx.x] = acc;
}

__global__ __launch_bounds__(128) void cumprod2_k(const float* __restrict__ gamma,
                                                  const float* __restrict__ segprod,
                                                  float* __restrict__ out) {
  const int bx = blockIdx.x;
  const int b = bx >> 7, h = (bx >> 3) & 15, seg = bx & 7;
  size_t base = (size_t)b * 4194304 + (size_t)h * 262144 + (size_t)seg * 256 * 128 + threadIdx.x;
  float pre = 1.f;
  const size_t sp0 = (size_t)(bx & ~7) * 128 + threadIdx.x;
  for (int t = 0; t < seg; ++t) pre *= segprod[sp0 + (size_t)t * 128];
  for (int s = 0; s < 256; ++s)
    out[base + (size_t)s * 128] = gamma[base + (size_t)s * 128] * pre;
}

// ---------------------------------------------------------------------------
// Memory attention: per (b,h), 32 query rows/block, M=64 mem tokens, dh=128.
// ---------------------------------------------------------------------------
__global__ __launch_bounds__(512) void attn_k(const short* __restrict__ qa,
                                              const short* __restrict__ ka,
                                              const short* __restrict__ va,
                                              short* __restrict__ ctx) {
  __shared__ short sk[64][136];
  __shared__ short sv[64][136];
  __shared__ float sq[32][128];
  __shared__ float ss[32][64];
  const int tid = threadIdx.x;
  const int b = blockIdx.z, h = blockIdx.y;
  const int s0 = blockIdx.x * 32;
  const size_t hoff = (size_t)h * 128;
  for (int i = tid; i < 64 * 128; i += 512) {
    int m = i >> 7, d = i & 127;
    sk[m][d] = ka[((size_t)b * 64 + m) * 2048 + hoff + d];
    sv[m][d] = va[((size_t)b * 64 + m) * 2048 + hoff + d];
  }
  for (int i = tid; i < 32 * 128; i += 512) {
    int s = i >> 7, d = i & 127;
    sq[s][d] = b2f(qa[((size_t)b * 2048 + s0 + s) * 2048 + hoff + d]);
  }
  __syncthreads();
  const int g = tid >> 4;  // query row within block
  const int t = tid & 15;
  float sc[4];
#pragma unroll
  for (int mi = 0; mi < 4; ++mi) {
    const int m = mi * 16 + t;
    float a = 0.f;
    for (int d = 0; d < 128; ++d) a += sq[g][d] * b2f(sk[m][d]);
    sc[mi] = a * 0.08838834764831843f;  // 1/sqrt(128)
  }
  float mx = fmaxf(fmaxf(sc[0], sc[1]), fmaxf(sc[2], sc[3]));
#pragma unroll
  for (int off = 8; off; off >>= 1) mx = fmaxf(mx, __shfl_xor(mx, off, 16));
  float sum = 0.f;
#pragma unroll
  for (int mi = 0; mi < 4; ++mi) { sc[mi] = __expf(sc[mi] - mx); sum += sc[mi]; }
#pragma unroll
  for (int off = 8; off; off >>= 1) sum += __shfl_xor(sum, off, 16);
  const float inv = 1.f / sum;
#pragma unroll
  for (int mi = 0; mi < 4; ++mi) ss[g][mi * 16 + t] = sc[mi] * inv;
  __syncthreads();
  const int d0 = t * 8;
  float o[8] = {};
  for (int m = 0; m < 64; ++m) {
    const float wgt = ss[g][m];
#pragma unroll
    for (int i = 0; i < 8; ++i) o[i] += wgt * b2f(sv[m][d0 + i]);
  }
  short* op = ctx + ((size_t)b * 2048 + s0 + g) * 2048 + hoff + d0;
#pragma unroll
  for (int i = 0; i < 8; ++i) op[i] = f2b(o[i]);
}

// ---------------------------------------------------------------------------
extern "C" void kernel_launch(void* const* d_in, const int* in_sizes, int n_in,
                              void* d_out, int out_size, void* d_ws, size_t ws_size,
                              hipStream_t stream) {
  (void)in_sizes; (void)n_in; (void)out_size; (void)ws_size;
  // inputs (setup_inputs dict order, all fp32); wq/bq and wv/bv are dead
  const float* x   = (const float*)d_in[0];
  const float* mem = (const float*)d_in[1];
  const float* wk  = (const float*)d_in[3];
  const float* wz  = (const float*)d_in[5];
  const float* wg  = (const float*)d_in[6];
  const float* md1 = (const float*)d_in[7];
  const float* md2 = (const float*)d_in[8];
  const float* mcw = (const float*)d_in[9];
  const float* awq = (const float*)d_in[10];
  const float* awk = (const float*)d_in[11];
  const float* awv = (const float*)d_in[12];
  const float* awo = (const float*)d_in[13];
  const float* f1  = (const float*)d_in[14];
  const float* f2  = (const float*)d_in[15];
  const float* bk  = (const float*)d_in[17];
  const float* bz  = (const float*)d_in[19];
  const float* bg  = (const float*)d_in[20];
  const float* mb1 = (const float*)d_in[21];
  const float* mb2 = (const float*)d_in[22];
  const float* mcb = (const float*)d_in[23];
  const float* abq = (const float*)d_in[24];
  const float* abk = (const float*)d_in[25];
  const float* abv = (const float*)d_in[26];
  const float* abo = (const float*)d_in[27];
  const float* fb1 = (const float*)d_in[28];
  const float* fb2 = (const float*)d_in[29];
  const float* n1w = (const float*)d_in[30];
  const float* n2w = (const float*)d_in[31];

  // workspace layout (bytes); total ~296 MB
  char* W = (char*)d_ws;
  short* wkT  = (short*)(W + 0);
  short* wzT  = (short*)(W + 8388608);
  short* wgT  = (short*)(W + 16777216);
  short* mcwT = (short*)(W + 25165824);
  short* md1T = (short*)(W + 33554432);
  short* md2T = (short*)(W + 35651584);
  short* awqT = (short*)(W + 37748736);
  short* awkT = (short*)(W + 46137344);
  short* awvT = (short*)(W + 54525952);
  short* awoT = (short*)(W + 62914560);
  short* f1T  = (short*)(W + 71303168);
  short* f2T  = (short*)(W + 104857600);
  char*  big  = W + 138412032;               // 64 MB region, reused as t2
  short* xn   = (short*)(big + 0);
  short* kk   = (short*)(big + 16777216);    // later: ctx
  short* z    = (short*)(big + 33554432);
  short* gpre = (short*)(big + 50331648);
  short* ctx  = kk;
  short* t2   = (short*)big;
  short* t1   = (short*)(W + 205520896);
  float* gamma = (float*)(W + 209715200);    // later: xres (fp32)
  float* xres  = gamma;
  short* ht   = (short*)(W + 243269632);
  short* qa   = (short*)(W + 260046848);
  short* xn2  = qa;
  short* xb   = (short*)(W + 276824064);
  short* memb = (short*)(W + 293601280);
  short* ka   = (short*)(W + 294125568);
  short* va   = (short*)(W + 294649856);
  float* segprod = (float*)(W + 295174144);

  float* out0 = (float*)d_out;               // output  (B,S,D) fp32
  float* out1 = out0 + 8388608;              // cumprod (B,S,D) fp32

  const dim3 tb16(16, 16);
  // 1) weight transposes (fp32 -> bf16, Bt layout [N][K])
  transpose_k<<<dim3(32, 32), tb16, 0, stream>>>(wk, wkT, 2048, 2048);
  transpose_k<<<dim3(32, 32), tb16, 0, stream>>>(wz, wzT, 2048, 2048);
  transpose_k<<<dim3(32, 32), tb16, 0, stream>>>(wg, wgT, 2048, 2048);
  transpose_k<<<dim3(32, 32), tb16, 0, stream>>>(mcw, mcwT, 2048, 2048);
  transpose_k<<<dim3(8, 32), tb16, 0, stream>>>(md1, md1T, 2048, 512);
  transpose_k<<<dim3(32, 8), tb16, 0, stream>>>(md2, md2T, 512, 2048);
  transpose_k<<<dim3(32, 32), tb16, 0, stream>>>(awq, awqT, 2048, 2048);
  transpose_k<<<dim3(32, 32), tb16, 0, stream>>>(awk, awkT, 2048, 2048);
  transpose_k<<<dim3(32, 32), tb16, 0, stream>>>(awv, awvT, 2048, 2048);
  transpose_k<<<dim3(32, 32), tb16, 0, stream>>>(awo, awoT, 2048, 2048);
  transpose_k<<<dim3(128, 32), tb16, 0, stream>>>(f1, f1T, 2048, 8192);
  transpose_k<<<dim3(32, 128), tb16, 0, stream>>>(f2, f2T, 8192, 2048);

  // 2) converts + first norm
  cvt_k<<<8192, 256, 0, stream>>>(x, xb);
  cvt_k<<<256, 256, 0, stream>>>(mem, memb);
  rmsnorm_k<<<4096, 256, 0, stream>>>(x, n1w, xn);

  // 3-5) projections (grid = (N/256, M/128), all nwg%8==0)
  gemm8_k<0><<<dim3(8, 32), 512, 0, stream>>>(xn, wkT, bk, kk, nullptr, nullptr, 4096, 2048, 2048);
  gemm8_k<0><<<dim3(8, 32), 512, 0, stream>>>(xn, wzT, bz, z, nullptr, nullptr, 4096, 2048, 2048);
  gemm8_k<0><<<dim3(8, 32), 512, 0, stream>>>(xb, wgT, bg, gpre, nullptr, nullptr, 4096, 2048, 2048);

  // 6-8) gamma = sigmoid(gelu(z@md1+mb1)@md2 + mb2 + k_@mcw + mcb)
  gemm8_k<1><<<dim3(2, 32), 512, 0, stream>>>(z, md1T, mb1, t1, nullptr, nullptr, 4096, 512, 2048);
  gemm8_k<2><<<dim3(8, 32), 512, 0, stream>>>(t1, md2T, mb2, gamma, nullptr, nullptr, 4096, 2048, 512);
  gemm8_k<3><<<dim3(8, 32), 512, 0, stream>>>(kk, mcwT, mcb, gamma, gamma, nullptr, 4096, 2048, 2048);

  // 9) h_t = z*sigmoid(gpre) + gamma*x   (before cumprod destroys gamma)
  ht_k<<<8192, 256, 0, stream>>>(z, gpre, gamma, x, ht);

  // 10-11) cumprod -> out1 (fp32)
  cumprod1_k<<<256, 128, 0, stream>>>(gamma, segprod);
  cumprod2_k<<<256, 128, 0, stream>>>(gamma, segprod, out1);

  // 12-14) attention projections
  gemm8_k<0><<<dim3(8, 32), 512, 0, stream>>>(ht, awqT, abq, qa, nullptr, nullptr, 4096, 2048, 2048);
  gemm8_k<0><<<dim3(8, 1), 512, 0, stream>>>(memb, awkT, abk, ka, nullptr, nullptr, 128, 2048, 2048);
  gemm8_k<0><<<dim3(8, 1), 512, 0, stream>>>(memb, awvT, abv, va, nullptr, nullptr, 128, 2048, 2048);

  // 15) attention -> ctx
  attn_k<<<dim3(64, 16, 2), 512, 0, stream>>>(qa, ka, va, ctx);

  // 16) xres = ctx@awo + abo + x + ht   (fp32)
  gemm8_k<4><<<dim3(8, 32), 512, 0, stream>>>(ctx, awoT, abo, xres, x, ht, 4096, 2048, 2048);

  // 17) xn2 = rmsnorm(xres, n2w)
  rmsnorm_k<<<4096, 256, 0, stream>>>(xres, n2w, xn2);

  // 18-19) FFN: out0 = xres + gelu(xn2@f1+fb1)@f2 + fb2
  gemm8_k<1><<<dim3(32, 32), 512, 0, stream>>>(xn2, f1T, fb1, t2, nullptr, nullptr, 4096, 8192, 2048);
  gemm8_k<5><<<dim3(8, 32), 512, 0, stream>>>(t2, f2T, fb2, out0, xres, nullptr, 4096, 2048, 8192);
}